// Round 17
// baseline (283.673 us; speedup 1.0000x reference)
//
#include <hip/hip_runtime.h>
#include <hip/hip_bf16.h>
#include <stdint.h>

// Attention_5265629905090: B=4, S=4096, D=256, fp32 in/out, int mask (1 = masked -> -1e9)
// R17: 32 q-rows/wave (4 waves x 32q = QBLK 128). K/V B-frags read once, reused across
// m=0,1 -> LDS read traffic HALVES (the quantity invariant across R7-R16's 155-178us).
// Regs ~300 unified -> 1 wave/SIMD, but LDS 143KB forces 1 block/CU anyway (regs free
// to 512 via launch_bounds(256,1)). gll staging (R14-proven pre-swizzled source) into
// dbuf LDS, single barrier, correct phase: issue t+1 right after barrier. Split x2.

typedef __attribute__((ext_vector_type(8))) short bf16x8;
typedef __attribute__((ext_vector_type(4))) float f32x4;

__device__ __forceinline__ short f2bf(float f) {
    union { float f; uint32_t u; } v; v.f = f;
    uint32_t r = v.u + 0x7FFFu + ((v.u >> 16) & 1u);   // RNE
    return (short)(r >> 16);
}
__device__ __forceinline__ float bf2f(short s) {
    union { uint32_t u; float f; } v; v.u = ((uint32_t)(uint16_t)s) << 16;
    return v.f;
}

// ---------------------------------------------------------------------------
// Projection GEMM: C[s][e] = sum_d X[s][d] * W[e][d]   (nn.Linear, y = x W^T)
// grid (128, 3), block 512 (8 waves x 16 rows).  proj: 0=Q (scaled 1/16), 1=K, 2=V^T
// ---------------------------------------------------------------------------
__global__ __launch_bounds__(512, 2)
void proj_kernel(const float* __restrict__ encq,
                 const float* __restrict__ enck,
                 const float* __restrict__ encv,
                 const float* __restrict__ Wq,
                 const float* __restrict__ Wk,
                 const float* __restrict__ Wv,
                 short* __restrict__ q_out,   // [16384][256]
                 short* __restrict__ k_out,   // [16384][256]
                 short* __restrict__ vt_out)  // [4][256][4096]
{
    __shared__ short As[128][72];
    __shared__ short Bs[256][72];

    const int tid = threadIdx.x;
    const int wave = tid >> 6, lane = tid & 63, lo = lane & 15, hi = lane >> 4;
    const int proj = blockIdx.y;
    const int row0 = blockIdx.x * 128;

    const float* X = (proj == 0) ? encq : (proj == 1) ? enck : encv;
    const float* W = (proj == 0) ? Wq   : (proj == 1) ? Wk   : Wv;

    f32x4 acc[16];
    #pragma unroll
    for (int n = 0; n < 16; ++n) {
        f32x4 z = {0.f, 0.f, 0.f, 0.f};
        acc[n] = z;
    }

    for (int ks = 0; ks < 4; ++ks) {
        const int k0 = ks * 64;
        __syncthreads();
        #pragma unroll
        for (int i = 0; i < 4; ++i) {
            int u = tid + i * 512;
            int r = u >> 4, c4 = u & 15;
            float4 v = *(const float4*)(X + (size_t)(row0 + r) * 256 + k0 + c4 * 4);
            short* dst = &As[r][c4 * 4];
            dst[0] = f2bf(v.x); dst[1] = f2bf(v.y); dst[2] = f2bf(v.z); dst[3] = f2bf(v.w);
        }
        #pragma unroll
        for (int i = 0; i < 8; ++i) {
            int u = tid + i * 512;
            int r = u >> 4, c4 = u & 15;
            float4 v = *(const float4*)(W + (size_t)r * 256 + k0 + c4 * 4);
            short* dst = &Bs[r][c4 * 4];
            dst[0] = f2bf(v.x); dst[1] = f2bf(v.y); dst[2] = f2bf(v.z); dst[3] = f2bf(v.w);
        }
        __syncthreads();
        #pragma unroll
        for (int kl = 0; kl < 2; ++kl) {
            bf16x8 a = *(const bf16x8*)&As[wave * 16 + lo][kl * 32 + hi * 8];
            #pragma unroll
            for (int n = 0; n < 16; ++n) {
                bf16x8 b = *(const bf16x8*)&Bs[n * 16 + lo][kl * 32 + hi * 8];
                acc[n] = __builtin_amdgcn_mfma_f32_16x16x32_bf16(a, b, acc[n], 0, 0, 0);
            }
        }
    }

    #pragma unroll
    for (int n = 0; n < 16; ++n)
        #pragma unroll
        for (int j = 0; j < 4; ++j) {
            int srow = row0 + wave * 16 + hi * 4 + j;
            int e = n * 16 + lo;
            float v = acc[n][j];
            if (proj == 0) {
                q_out[(size_t)srow * 256 + e] = f2bf(v * 0.0625f);
            } else if (proj == 1) {
                k_out[(size_t)srow * 256 + e] = f2bf(v);
            } else {
                int b = srow >> 12, s = srow & 4095;
                vt_out[((size_t)b * 256 + e) * 4096 + s] = f2bf(v);
            }
        }
}

// ---------------------------------------------------------------------------
// Flash attention, split-KV x2. grid (32, 4, 2), block 256 (4 waves x 32 q-rows,
// QBLK=128). KVBLK = 64, 32 tiles/block. LDS 143360 B dbuf, 1 block/CU.
// gll staging (pre-swizzled source, linear dest, swizzled read); single barrier
// per iter; fused mask bit-pack -> dbuf u64 bitmap; defer-max; L via ones-MFMA.
// ---------------------------------------------------------------------------
__global__ __launch_bounds__(256, 1)
void attn_kernel(const short* __restrict__ qs,   // [16384][256] prescaled
                 const short* __restrict__ kk_,  // [16384][256]
                 const short* __restrict__ vt,   // [4][256][4096]
                 const int*   __restrict__ mask, // [4][4096][4096]
                 short* __restrict__ Opart,      // [2][16384][256] bf16
                 float* __restrict__ Mpart,      // [2][16384]
                 float* __restrict__ Lpart)      // [2][16384]
{
    __shared__ short Ks[2][64 * 256];           // 2 x 32768 B, slot(row,u)=K[row][u^(row&7)]
    __shared__ short Vs[2][256 * 64];           // 2 x 32768 B, slot(r,u)=V^T[r][u^(r&7)]
    __shared__ short Ps[4][32][40];             // 10240 B per-wave P buffer
    __shared__ unsigned long long Mb[2][128];   //  2048 B dbuf bitmap   (total 143360)

    const int tid = threadIdx.x;
    const int wave = tid >> 6, lane = tid & 63, lo = lane & 15, hi = lane >> 4;
    const int qt = blockIdx.x, b = blockIdx.y, split = blockIdx.z;
    const int qrow0 = qt * 128 + wave * 32;           // q row base within batch
    const size_t qg0 = (size_t)b * 4096 + qrow0;      // global q row base
    const int kv0 = split * 2048;

    // resident Q fragments (32 rows = 2 x 16): A-frag row = lane&15
    bf16x8 qf[2][8];
    #pragma unroll
    for (int m = 0; m < 2; ++m)
        #pragma unroll
        for (int kk = 0; kk < 8; ++kk)
            qf[m][kk] = *(const bf16x8*)(qs + (qg0 + m * 16 + lo) * 256 + kk * 32 + hi * 8);

    f32x4 oacc[2][16];
    #pragma unroll
    for (int m = 0; m < 2; ++m)
        #pragma unroll
        for (int n = 0; n < 16; ++n) {
            f32x4 z = {0.f, 0.f, 0.f, 0.f};
            oacc[m][n] = z;
        }
    float Mst[2][4], Lst[2][4];
    #pragma unroll
    for (int m = 0; m < 2; ++m)
        #pragma unroll
        for (int j = 0; j < 4; ++j) { Mst[m][j] = -1e30f; Lst[m][j] = 0.f; }

    bf16x8 onesf;
    #pragma unroll
    for (int i = 0; i < 8; ++i) onesf[i] = (short)0x3F80;   // bf16 1.0

    const short* ksrc0 = kk_ + ((size_t)b * 4096 + kv0) * 256;
    const short* vsrc0 = vt + (size_t)b * 256 * 4096;
    // mask staging: thread owns (row = tid>>1, half = tid&1): 32 consecutive ints
    const int mrow = tid >> 1, mpart = tid & 1;
    const int* msrc0 = mask + (size_t)b * 4096 * 4096
                     + (size_t)(qt * 128 + mrow) * 4096 + kv0 + mpart * 32;

    // stage tile t into buffer t&1 via global_load_lds (linear dest, swizzled src)
    auto stage = [&](int t) {
        const int bi = t & 1;
        const short* kt = ksrc0 + (size_t)t * 64 * 256;
        #pragma unroll
        for (int i = 0; i < 8; ++i) {
            int sbase = i * 256 + wave * 64;     // wave-uniform chunk base (16B slots)
            int s = sbase + lane;
            int r = s >> 5, wu = s & 31;
            const short* g = kt + r * 256 + ((wu ^ (r & 7)) << 3);
            __builtin_amdgcn_global_load_lds((const void*)g, (void*)&Ks[bi][sbase * 8], 16, 0, 0);
        }
        const int c0 = kv0 + t * 64;
        #pragma unroll
        for (int i = 0; i < 8; ++i) {
            int sbase = i * 256 + wave * 64;
            int s = sbase + lane;
            int r = s >> 3, vu = s & 7;          // 8 slots per 64-kv d-row
            const short* g = vsrc0 + (size_t)r * 4096 + c0 + ((vu ^ (r & 7)) << 3);
            __builtin_amdgcn_global_load_lds((const void*)g, (void*)&Vs[bi][sbase * 8], 16, 0, 0);
        }
    };

    int4 mreg[8];
    auto mload = [&](int t) {
        const int* ms = msrc0 + (size_t)t * 64;
        #pragma unroll
        for (int i = 0; i < 8; ++i)
            mreg[i] = *(const int4*)(ms + i * 4);
    };
    auto mcommit = [&](int bi) {
        uint32_t mb = 0;
        #pragma unroll
        for (int i = 0; i < 8; ++i) {
            mb |= (uint32_t)(mreg[i].x != 0) << (i * 4);
            mb |= (uint32_t)(mreg[i].y != 0) << (i * 4 + 1);
            mb |= (uint32_t)(mreg[i].z != 0) << (i * 4 + 2);
            mb |= (uint32_t)(mreg[i].w != 0) << (i * 4 + 3);
        }
        ((uint32_t*)&Mb[bi][mrow])[mpart] = mb;
    };

    // --- prologue ---
    stage(0);
    mload(0);

    for (int t = 0; t < 32; ++t) {
        const int bi = t & 1;
        mcommit(bi);       // bitmap for tile t (waits only on this wave's mask loads)
        __syncthreads();   // drains gll(t) -> buf bi; Mb[bi] visible; compute(t-1) done
                           // (so gll(t+1) below may overwrite buf bi^1)
        if (t < 31) {
            stage(t + 1);  // full compute(t) of flight time
            mload(t + 1);  // mreg free: committed above
        }

        // --- mask bit-words: block-local row = wave*32 + m*16 + hi*4 + j ---
        unsigned long long wls[2][4];
        #pragma unroll
        for (int m = 0; m < 2; ++m)
            #pragma unroll
            for (int j = 0; j < 4; ++j)
                wls[m][j] = Mb[bi][wave * 32 + m * 16 + hi * 4 + j] >> lo;

        // --- QK^T: S[32q][64k]; B-frag read once, reused for m=0,1 ---
        f32x4 sacc[2][4];
        #pragma unroll
        for (int m = 0; m < 2; ++m)
            #pragma unroll
            for (int n = 0; n < 4; ++n) {
                f32x4 z = {0.f, 0.f, 0.f, 0.f};
                sacc[m][n] = z;
            }
        #pragma unroll
        for (int kk = 0; kk < 8; ++kk) {
            #pragma unroll
            for (int n = 0; n < 4; ++n) {
                int row = n * 16 + lo;
                bf16x8 bk = *(const bf16x8*)&Ks[bi][row * 256 + ((kk * 4 + hi) ^ (lo & 7)) * 8];
                #pragma unroll
                for (int m = 0; m < 2; ++m)
                    sacc[m][n] = __builtin_amdgcn_mfma_f32_16x16x32_bf16(qf[m][kk], bk, sacc[m][n], 0, 0, 0);
            }
        }

        // --- row max (masked), butterfly over the 16-lane column group ---
        float ml[2][4];
        #pragma unroll
        for (int m = 0; m < 2; ++m)
            #pragma unroll
            for (int j = 0; j < 4; ++j) {
                float mx = -1e30f;
                #pragma unroll
                for (int n = 0; n < 4; ++n) {
                    float s = sacc[m][n][j];
                    if ((wls[m][j] >> (n * 16)) & 1ull) s = -1e30f;
                    mx = fmaxf(mx, s);
                }
                #pragma unroll
                for (int d = 1; d < 16; d <<= 1)
                    mx = fmaxf(mx, __shfl_xor(mx, d));
                ml[m][j] = mx;
            }

        // --- defer-max rescale (THR = 8) ---
        bool needl = false;
        #pragma unroll
        for (int m = 0; m < 2; ++m)
            #pragma unroll
            for (int j = 0; j < 4; ++j)
                needl = needl || (ml[m][j] > Mst[m][j] + 8.0f);
        if (__any((int)needl)) {
            #pragma unroll
            for (int m = 0; m < 2; ++m)
                #pragma unroll
                for (int j = 0; j < 4; ++j) {
                    float Mn = fmaxf(Mst[m][j], ml[m][j]);
                    float sc = __expf(Mst[m][j] - Mn);
                    Mst[m][j] = Mn;
                    Lst[m][j] *= sc;
                    #pragma unroll
                    for (int n = 0; n < 16; ++n) oacc[m][n][j] *= sc;
                }
        }

        // --- PV in two k-halves; V B-frag read once, reused for m=0,1 ---
        f32x4 lacc[2];
        {
            f32x4 z = {0.f, 0.f, 0.f, 0.f};
            lacc[0] = z; lacc[1] = z;
        }
        #pragma unroll
        for (int g = 0; g < 2; ++g) {
            #pragma unroll
            for (int m = 0; m < 2; ++m)
                #pragma unroll
                for (int nn = 0; nn < 2; ++nn) {
                    int n = g * 2 + nn;
                    #pragma unroll
                    for (int j = 0; j < 4; ++j) {
                        float p = __expf(sacc[m][n][j] - Mst[m][j]);
                        if ((wls[m][j] >> (n * 16)) & 1ull) p = 0.0f;
                        Ps[wave][m * 16 + hi * 4 + j][nn * 16 + lo] = f2bf(p);
                    }
                }
            bf16x8 a2[2];
            #pragma unroll
            for (int m = 0; m < 2; ++m)
                a2[m] = *(const bf16x8*)&Ps[wave][m * 16 + lo][hi * 8];
            #pragma unroll
            for (int n = 0; n < 16; ++n) {
                int row = n * 16 + lo;
                bf16x8 bv = *(const bf16x8*)&Vs[bi][row * 64 + ((g * 4 + hi) ^ (lo & 7)) * 8];
                #pragma unroll
                for (int m = 0; m < 2; ++m)
                    oacc[m][n] = __builtin_amdgcn_mfma_f32_16x16x32_bf16(a2[m], bv, oacc[m][n], 0, 0, 0);
            }
            #pragma unroll
            for (int m = 0; m < 2; ++m)
                lacc[m] = __builtin_amdgcn_mfma_f32_16x16x32_bf16(a2[m], onesf, lacc[m], 0, 0, 0);
        }
        #pragma unroll
        for (int m = 0; m < 2; ++m)
            #pragma unroll
            for (int j = 0; j < 4; ++j)
                Lst[m][j] += lacc[m][j];
    }

    // --- epilogue: bf16 raw partials ---
    const size_t obase = ((size_t)split * 16384 + qg0) * 256;
    #pragma unroll
    for (int m = 0; m < 2; ++m)
        #pragma unroll
        for (int n = 0; n < 16; ++n)
            #pragma unroll
            for (int j = 0; j < 4; ++j)
                Opart[obase + (size_t)(m * 16 + hi * 4 + j) * 256 + n * 16 + lo] =
                    f2bf(oacc[m][n][j]);
    if (lo == 0) {
        #pragma unroll
        for (int m = 0; m < 2; ++m)
            #pragma unroll
            for (int j = 0; j < 4; ++j) {
                size_t r = (size_t)split * 16384 + qg0 + m * 16 + hi * 4 + j;
                Mpart[r] = Mst[m][j];
                Lpart[r] = Lst[m][j];
            }
    }
}

// ---------------------------------------------------------------------------
// Combine the two KV-split partials.  grid 4096, block 256, 4 floats/thread.
// ---------------------------------------------------------------------------
__global__ __launch_bounds__(256)
void combine_kernel(const short* __restrict__ Opart,
                    const float* __restrict__ Mpart,
                    const float* __restrict__ Lpart,
                    float* __restrict__ out)
{
    int gid = blockIdx.x * 256 + threadIdx.x;   // 1,048,576 threads
    int row = gid >> 6, c4 = gid & 63;
    float M0 = Mpart[row], M1 = Mpart[16384 + row];
    float L0 = Lpart[row], L1 = Lpart[16384 + row];
    float M = fmaxf(M0, M1);
    float w0 = __expf(M0 - M), w1 = __expf(M1 - M);
    float inv = 1.0f / (w0 * L0 + w1 * L1);
    short4 o0 = *(const short4*)(Opart + (size_t)row * 256 + c4 * 4);
    short4 o1 = *(const short4*)(Opart + (size_t)16384 * 256 + (size_t)row * 256 + c4 * 4);
    float4 r;
    r.x = (w0 * bf2f(o0.x) + w1 * bf2f(o1.x)) * inv;
    r.y = (w0 * bf2f(o0.y) + w1 * bf2f(o1.y)) * inv;
    r.z = (w0 * bf2f(o0.z) + w1 * bf2f(o1.z)) * inv;
    r.w = (w0 * bf2f(o0.w) + w1 * bf2f(o1.w)) * inv;
    *(float4*)(out + (size_t)row * 256 + c4 * 4) = r;
}

// ---------------------------------------------------------------------------
extern "C" void kernel_launch(void* const* d_in, const int* in_sizes, int n_in,
                              void* d_out, int out_size, void* d_ws, size_t ws_size,
                              hipStream_t stream)
{
    const float* encq = (const float*)d_in[0];
    const float* enck = (const float*)d_in[1];
    const float* encv = (const float*)d_in[2];
    const int*   mask = (const int*)d_in[3];
    const float* Wq   = (const float*)d_in[4];
    const float* Wk   = (const float*)d_in[5];
    const float* Wv   = (const float*)d_in[6];

    char* ws = (char*)d_ws;
    short* q_ws  = (short*)(ws);                  //  8 MB  [16384][256] bf16
    short* k_ws  = (short*)(ws + 8388608);        //  8 MB
    short* vt_ws = (short*)(ws + 16777216);       //  8 MB  [4][256][4096] bf16
    short* Opart = (short*)(ws + 25165824);       // 16 MB  [2][16384][256] bf16
    float* Mpart = (float*)(ws + 41943040);       // 128 KB [2][16384]
    float* Lpart = (float*)(ws + 42074112);       // 128 KB  (total ~40.5 MB)
    float* out   = (float*)d_out;

    hipLaunchKernelGGL(proj_kernel, dim3(128, 3), dim3(512), 0, stream,
                       encq, enck, encv, Wq, Wk, Wv, q_ws, k_ws, vt_ws);
    hipLaunchKernelGGL(attn_kernel, dim3(32, 4, 2), dim3(256), 0, stream,
                       q_ws, k_ws, vt_ws, mask, Opart, Mpart, Lpart);
    hipLaunchKernelGGL(combine_kernel, dim3(4096), dim3(256), 0, stream,
                       Opart, Mpart, Lpart, out);
}

// Round 18
// 193.861 us; speedup vs baseline: 1.4633x; 1.4633x over previous
//
#include <hip/hip_runtime.h>
#include <hip/hip_bf16.h>
#include <stdint.h>

// Attention_5265629905090: B=4, S=4096, D=256, fp32 in/out, int mask (1 = masked -> -1e9)
// R18: LOCK-IN of R11, the measured optimum (total 194us; attn 159us). Structural ceiling
// established over R10-R17: >155us attn requires 16 waves/CU -> <=128 unified regs/wave,
// but per-wave state (qf32+oacc64+addr) can't fit without spills (R12: 2.3x cost) or
// halved output + duplicated QK (R15: net loss). 8 waves/CU is the operating point;
// traffic (R17), conflicts (R11), barriers (R16), staging style (R14) all secondary.

typedef __attribute__((ext_vector_type(8))) short bf16x8;
typedef __attribute__((ext_vector_type(4))) float f32x4;

__device__ __forceinline__ short f2bf(float f) {
    union { float f; uint32_t u; } v; v.f = f;
    uint32_t r = v.u + 0x7FFFu + ((v.u >> 16) & 1u);   // RNE
    return (short)(r >> 16);
}
__device__ __forceinline__ float bf2f(short s) {
    union { uint32_t u; float f; } v; v.u = ((uint32_t)(uint16_t)s) << 16;
    return v.f;
}

// ---------------------------------------------------------------------------
// Projection GEMM: C[s][e] = sum_d X[s][d] * W[e][d]   (nn.Linear, y = x W^T)
// grid (128, 3), block 512 (8 waves x 16 rows).  proj: 0=Q (scaled 1/16), 1=K, 2=V^T
// ---------------------------------------------------------------------------
__global__ __launch_bounds__(512, 2)
void proj_kernel(const float* __restrict__ encq,
                 const float* __restrict__ enck,
                 const float* __restrict__ encv,
                 const float* __restrict__ Wq,
                 const float* __restrict__ Wk,
                 const float* __restrict__ Wv,
                 short* __restrict__ q_out,   // [16384][256]
                 short* __restrict__ k_out,   // [16384][256]
                 short* __restrict__ vt_out)  // [4][256][4096]
{
    __shared__ short As[128][72];
    __shared__ short Bs[256][72];

    const int tid = threadIdx.x;
    const int wave = tid >> 6, lane = tid & 63, lo = lane & 15, hi = lane >> 4;
    const int proj = blockIdx.y;
    const int row0 = blockIdx.x * 128;

    const float* X = (proj == 0) ? encq : (proj == 1) ? enck : encv;
    const float* W = (proj == 0) ? Wq   : (proj == 1) ? Wk   : Wv;

    f32x4 acc[16];
    #pragma unroll
    for (int n = 0; n < 16; ++n) {
        f32x4 z = {0.f, 0.f, 0.f, 0.f};
        acc[n] = z;
    }

    for (int ks = 0; ks < 4; ++ks) {
        const int k0 = ks * 64;
        __syncthreads();
        #pragma unroll
        for (int i = 0; i < 4; ++i) {
            int u = tid + i * 512;
            int r = u >> 4, c4 = u & 15;
            float4 v = *(const float4*)(X + (size_t)(row0 + r) * 256 + k0 + c4 * 4);
            short* dst = &As[r][c4 * 4];
            dst[0] = f2bf(v.x); dst[1] = f2bf(v.y); dst[2] = f2bf(v.z); dst[3] = f2bf(v.w);
        }
        #pragma unroll
        for (int i = 0; i < 8; ++i) {
            int u = tid + i * 512;
            int r = u >> 4, c4 = u & 15;
            float4 v = *(const float4*)(W + (size_t)r * 256 + k0 + c4 * 4);
            short* dst = &Bs[r][c4 * 4];
            dst[0] = f2bf(v.x); dst[1] = f2bf(v.y); dst[2] = f2bf(v.z); dst[3] = f2bf(v.w);
        }
        __syncthreads();
        #pragma unroll
        for (int kl = 0; kl < 2; ++kl) {
            bf16x8 a = *(const bf16x8*)&As[wave * 16 + lo][kl * 32 + hi * 8];
            #pragma unroll
            for (int n = 0; n < 16; ++n) {
                bf16x8 b = *(const bf16x8*)&Bs[n * 16 + lo][kl * 32 + hi * 8];
                acc[n] = __builtin_amdgcn_mfma_f32_16x16x32_bf16(a, b, acc[n], 0, 0, 0);
            }
        }
    }

    #pragma unroll
    for (int n = 0; n < 16; ++n)
        #pragma unroll
        for (int j = 0; j < 4; ++j) {
            int srow = row0 + wave * 16 + hi * 4 + j;
            int e = n * 16 + lo;
            float v = acc[n][j];
            if (proj == 0) {
                q_out[(size_t)srow * 256 + e] = f2bf(v * 0.0625f);
            } else if (proj == 1) {
                k_out[(size_t)srow * 256 + e] = f2bf(v);
            } else {
                int b = srow >> 12, s = srow & 4095;
                vt_out[((size_t)b * 256 + e) * 4096 + s] = f2bf(v);
            }
        }
}

// ---------------------------------------------------------------------------
// Flash attention, split-KV x4. grid (32, 4, 4), block 512 (8 waves x 16 q-rows).
// KVBLK = 64, 16 tiles/block. LDS 76800 B (XOR-swizzled Ks/Vs, no padding).
// T14 async staging for K, V^T, raw mask (fused bit-pack bitmap).
// Swizzle: 16B-unit index ^= (row & 7), same involution on write and read.
// ---------------------------------------------------------------------------
__global__ __launch_bounds__(512, 2)
void attn_kernel(const short* __restrict__ qs,   // [16384][256] prescaled
                 const short* __restrict__ kk_,  // [16384][256]
                 const short* __restrict__ vt,   // [4][256][4096]
                 const int*   __restrict__ mask, // [4][4096][4096]
                 short* __restrict__ Opart,      // [4][16384][256] bf16
                 float* __restrict__ Mpart,      // [4][16384]
                 float* __restrict__ Lpart)      // [4][16384]
{
    __shared__ short Ks[64 * 256];              // 32768 B, swizzled
    __shared__ short Vs[256 * 64];              // 32768 B, swizzled
    __shared__ short Ps[8][16][40];             // 10240 B
    __shared__ unsigned long long Mb[128];      //  1024 B   (total 76800)

    const int tid = threadIdx.x;
    const int wave = tid >> 6, lane = tid & 63, lo = lane & 15, hi = lane >> 4;
    const int qt = blockIdx.x, b = blockIdx.y, split = blockIdx.z;
    const int qrow0 = qt * 128 + wave * 16;           // q row base within batch
    const size_t qg0 = (size_t)b * 4096 + qrow0;      // global q row base
    const int kv0 = split * 1024;

    // resident Q fragments (16 rows): A-frag row = lane&15, k = (lane>>4)*8..+8
    bf16x8 qf[8];
    #pragma unroll
    for (int kk = 0; kk < 8; ++kk)
        qf[kk] = *(const bf16x8*)(qs + (qg0 + lo) * 256 + kk * 32 + hi * 8);

    f32x4 oacc[16];
    #pragma unroll
    for (int n = 0; n < 16; ++n) {
        f32x4 z = {0.f, 0.f, 0.f, 0.f};
        oacc[n] = z;
    }
    float Mst[4], Lst[4];
    #pragma unroll
    for (int j = 0; j < 4; ++j) { Mst[j] = -1e30f; Lst[j] = 0.f; }

    bf16x8 onesf;
    #pragma unroll
    for (int i = 0; i < 8; ++i) onesf[i] = (short)0x3F80;   // bf16 1.0

    const short* ksrc0 = kk_ + ((size_t)b * 4096 + kv0) * 256;
    const size_t vbase = (size_t)b * 256 * 4096;
    // mask staging: thread owns (row = tid>>2, part = tid&3): 16 consecutive ints
    const int mrow = tid >> 2, mpart = tid & 3;
    const int* msrc0 = mask + (size_t)b * 4096 * 4096
                     + (size_t)(qt * 128 + mrow) * 4096 + kv0 + mpart * 16;

    // --- prologue: issue t=0 staging loads into regs ---
    bf16x8 kreg[4], vreg[4];
    int4 mreg[4];
    #pragma unroll
    for (int i = 0; i < 4; ++i) {
        int u = tid + i * 512;
        kreg[i] = *(const bf16x8*)(ksrc0 + u * 8);
    }
    #pragma unroll
    for (int i = 0; i < 4; ++i) {
        int u = tid + i * 512;
        int r = u >> 3, cu = u & 7;
        vreg[i] = *(const bf16x8*)(vt + vbase + (size_t)r * 4096 + kv0 + cu * 8);
    }
    #pragma unroll
    for (int i = 0; i < 4; ++i)
        mreg[i] = *(const int4*)(msrc0 + i * 4);

    for (int t = 0; t < 16; ++t) {
        __syncthreads();   // prior iteration done reading Ks/Vs/Mb
        // --- commit staged regs to LDS (swizzled) ---
        #pragma unroll
        for (int i = 0; i < 4; ++i) {
            int u = tid + i * 512;
            int row = u >> 5, unit = u & 31;
            *(bf16x8*)&Ks[row * 256 + (unit ^ (row & 7)) * 8] = kreg[i];
        }
        #pragma unroll
        for (int i = 0; i < 4; ++i) {
            int u = tid + i * 512;
            int r = u >> 3, cu = u & 7;
            *(bf16x8*)&Vs[r * 64 + (cu ^ (r & 7)) * 8] = vreg[i];
        }
        {
            uint32_t mb = 0;
            #pragma unroll
            for (int i = 0; i < 4; ++i) {
                mb |= (uint32_t)(mreg[i].x != 0) << (i * 4);
                mb |= (uint32_t)(mreg[i].y != 0) << (i * 4 + 1);
                mb |= (uint32_t)(mreg[i].z != 0) << (i * 4 + 2);
                mb |= (uint32_t)(mreg[i].w != 0) << (i * 4 + 3);
            }
            ((unsigned short*)&Mb[mrow])[mpart] = (unsigned short)mb;
        }
        __syncthreads();   // LDS tile + bitmap ready; staged regs reusable

        // --- issue t+1 staging loads; in flight during compute below ---
        if (t < 15) {
            const short* src = ksrc0 + (size_t)(t + 1) * 64 * 256;
            #pragma unroll
            for (int i = 0; i < 4; ++i) {
                int u = tid + i * 512;
                kreg[i] = *(const bf16x8*)(src + u * 8);
            }
            const int c0 = kv0 + (t + 1) * 64;
            #pragma unroll
            for (int i = 0; i < 4; ++i) {
                int u = tid + i * 512;
                int r = u >> 3, cu = u & 7;
                vreg[i] = *(const bf16x8*)(vt + vbase + (size_t)r * 4096 + c0 + cu * 8);
            }
            const int* ms = msrc0 + (t + 1) * 64;
            #pragma unroll
            for (int i = 0; i < 4; ++i)
                mreg[i] = *(const int4*)(ms + i * 4);
        }

        // --- mask bit-words from LDS bitmap: row wave*16+hi*4+j, bits >> lo ---
        unsigned long long wls[4];
        #pragma unroll
        for (int j = 0; j < 4; ++j)
            wls[j] = Mb[wave * 16 + hi * 4 + j] >> lo;

        // --- QK^T: S[16q][64k] ---
        f32x4 sacc[4];
        #pragma unroll
        for (int n = 0; n < 4; ++n) {
            f32x4 z = {0.f, 0.f, 0.f, 0.f};
            sacc[n] = z;
        }
        #pragma unroll
        for (int kk = 0; kk < 8; ++kk) {
            #pragma unroll
            for (int n = 0; n < 4; ++n) {
                int row = n * 16 + lo;
                bf16x8 bk = *(const bf16x8*)&Ks[row * 256 + ((kk * 4 + hi) ^ (lo & 7)) * 8];
                sacc[n] = __builtin_amdgcn_mfma_f32_16x16x32_bf16(qf[kk], bk, sacc[n], 0, 0, 0);
            }
        }

        // --- row max (masked), butterfly over the 16-lane column group ---
        float ml[4];
        #pragma unroll
        for (int j = 0; j < 4; ++j) {
            float mx = -1e30f;
            #pragma unroll
            for (int n = 0; n < 4; ++n) {
                float s = sacc[n][j];
                if ((wls[j] >> (n * 16)) & 1ull) s = -1e30f;
                mx = fmaxf(mx, s);
            }
            #pragma unroll
            for (int d = 1; d < 16; d <<= 1)
                mx = fmaxf(mx, __shfl_xor(mx, d));
            ml[j] = mx;
        }

        // --- defer-max rescale (THR = 8) ---
        bool needl = false;
        #pragma unroll
        for (int j = 0; j < 4; ++j)
            needl = needl || (ml[j] > Mst[j] + 8.0f);
        if (__any((int)needl)) {
            #pragma unroll
            for (int j = 0; j < 4; ++j) {
                float Mn = fmaxf(Mst[j], ml[j]);
                float sc = __expf(Mst[j] - Mn);
                Mst[j] = Mn;
                Lst[j] *= sc;
                #pragma unroll
                for (int n = 0; n < 16; ++n) oacc[n][j] *= sc;
            }
        }

        // --- PV in two k-halves through the per-wave P buffer ---
        f32x4 lacc = {0.f, 0.f, 0.f, 0.f};
        #pragma unroll
        for (int g = 0; g < 2; ++g) {
            #pragma unroll
            for (int nn = 0; nn < 2; ++nn) {
                int n = g * 2 + nn;
                #pragma unroll
                for (int j = 0; j < 4; ++j) {
                    float p = __expf(sacc[n][j] - Mst[j]);
                    if ((wls[j] >> (n * 16)) & 1ull) p = 0.0f;
                    Ps[wave][hi * 4 + j][nn * 16 + lo] = f2bf(p);
                }
            }
            bf16x8 a2 = *(const bf16x8*)&Ps[wave][lo][hi * 8];
            #pragma unroll
            for (int n = 0; n < 16; ++n) {
                int row = n * 16 + lo;
                bf16x8 bv = *(const bf16x8*)&Vs[row * 64 + ((g * 4 + hi) ^ (lo & 7)) * 8];
                oacc[n] = __builtin_amdgcn_mfma_f32_16x16x32_bf16(a2, bv, oacc[n], 0, 0, 0);
            }
            lacc = __builtin_amdgcn_mfma_f32_16x16x32_bf16(a2, onesf, lacc, 0, 0, 0);
        }
        #pragma unroll
        for (int j = 0; j < 4; ++j)
            Lst[j] += lacc[j];
    }

    // --- epilogue: bf16 raw partials ---
    const size_t obase = ((size_t)split * 16384 + qg0) * 256;
    #pragma unroll
    for (int n = 0; n < 16; ++n)
        #pragma unroll
        for (int j = 0; j < 4; ++j)
            Opart[obase + (size_t)(hi * 4 + j) * 256 + n * 16 + lo] = f2bf(oacc[n][j]);
    if (lo == 0) {
        #pragma unroll
        for (int j = 0; j < 4; ++j) {
            size_t r = (size_t)split * 16384 + qg0 + hi * 4 + j;
            Mpart[r] = Mst[j];
            Lpart[r] = Lst[j];
        }
    }
}

// ---------------------------------------------------------------------------
// Combine the four KV-split partials.  grid 4096, block 256, 4 floats/thread.
// ---------------------------------------------------------------------------
__global__ __launch_bounds__(256)
void combine_kernel(const short* __restrict__ Opart,
                    const float* __restrict__ Mpart,
                    const float* __restrict__ Lpart,
                    float* __restrict__ out)
{
    int gid = blockIdx.x * 256 + threadIdx.x;   // 1,048,576 threads
    int row = gid >> 6, c4 = gid & 63;
    float Ms[4], Ls[4], M = -1e30f;
    #pragma unroll
    for (int sp = 0; sp < 4; ++sp) {
        Ms[sp] = Mpart[sp * 16384 + row];
        Ls[sp] = Lpart[sp * 16384 + row];
        M = fmaxf(M, Ms[sp]);
    }
    float w[4], denom = 0.f;
    #pragma unroll
    for (int sp = 0; sp < 4; ++sp) {
        w[sp] = __expf(Ms[sp] - M);
        denom += w[sp] * Ls[sp];
    }
    float inv = 1.0f / denom;
    float4 r = {0.f, 0.f, 0.f, 0.f};
    #pragma unroll
    for (int sp = 0; sp < 4; ++sp) {
        short4 o = *(const short4*)(Opart + ((size_t)sp * 16384 + row) * 256 + c4 * 4);
        r.x += w[sp] * bf2f(o.x);
        r.y += w[sp] * bf2f(o.y);
        r.z += w[sp] * bf2f(o.z);
        r.w += w[sp] * bf2f(o.w);
    }
    r.x *= inv; r.y *= inv; r.z *= inv; r.w *= inv;
    *(float4*)(out + (size_t)row * 256 + c4 * 4) = r;
}

// ---------------------------------------------------------------------------
extern "C" void kernel_launch(void* const* d_in, const int* in_sizes, int n_in,
                              void* d_out, int out_size, void* d_ws, size_t ws_size,
                              hipStream_t stream)
{
    const float* encq = (const float*)d_in[0];
    const float* enck = (const float*)d_in[1];
    const float* encv = (const float*)d_in[2];
    const int*   mask = (const int*)d_in[3];
    const float* Wq   = (const float*)d_in[4];
    const float* Wk   = (const float*)d_in[5];
    const float* Wv   = (const float*)d_in[6];

    char* ws = (char*)d_ws;
    short* q_ws  = (short*)(ws);                  //  8 MB  [16384][256] bf16
    short* k_ws  = (short*)(ws + 8388608);        //  8 MB
    short* vt_ws = (short*)(ws + 16777216);       //  8 MB  [4][256][4096] bf16
    short* Opart = (short*)(ws + 25165824);       // 32 MB  [4][16384][256] bf16
    float* Mpart = (float*)(ws + 58720256);       // 256 KB [4][16384]
    float* Lpart = (float*)(ws + 58982400);       // 256 KB  (total ~58.2 MB)
    float* out   = (float*)d_out;

    hipLaunchKernelGGL(proj_kernel, dim3(128, 3), dim3(512), 0, stream,
                       encq, enck, encv, Wq, Wk, Wv, q_ws, k_ws, vt_ws);
    hipLaunchKernelGGL(attn_kernel, dim3(32, 4, 4), dim3(512), 0, stream,
                       q_ws, k_ws, vt_ws, mask, Opart, Mpart, Lpart);
    hipLaunchKernelGGL(combine_kernel, dim3(4096), dim3(256), 0, stream,
                       Opart, Mpart, Lpart, out);
}